// Round 10
// baseline (492.362 us; speedup 1.0000x reference)
//
#include <hip/hip_runtime.h>
#include <hip/hip_bf16.h>
#include <cstdint>
#include <cstddef>

#define NN 50000
#define EE 800000
#define FIN 512
#define HIDC 16
#define NH 8
#define HCH 128
#define NLBL 40
#define NLBLP 48
#define ETOT (EE + NN)
#define NEG_SLOPE 0.2f
#define ELU_A 0.2f
#define BN_EPS 1e-5f
#define SCH 8192
#define NCHK 7          // ceil(NN/SCH)
#define BSH 8           // bin = dst >> 8
#define BINS 196        // ceil(NN/256)
#define BCH 4096        // edges per k_bin block
#define GBIN ((ETOT + BCH - 1) / BCH)   // 208

typedef __attribute__((ext_vector_type(8))) short bf16x8;
typedef __attribute__((ext_vector_type(4))) short bf16x4;
typedef __attribute__((ext_vector_type(4))) float f32x4;

__device__ inline short f2b(float f) {
    __hip_bfloat16 h = __float2bfloat16(f);   // RNE
    return *reinterpret_cast<short*>(&h);
}
__device__ inline float blo(unsigned int u) {
    union { unsigned int u; float f; } v; v.u = u << 16; return v.f;
}
__device__ inline float bhi(unsigned int u) {
    union { unsigned int u; float f; } v; v.u = u & 0xffff0000u; return v.f;
}

// ---------------- fused prep: weight transposes + degree hist + bin hist ----------------
// Scatter write-amplification fix (round-9: k_scatter 60us, WRITE 54.8MB for 3.4MB payload):
// edges get binned by dst>>8 first, so the final scatter writes land in per-bin contiguous
// windows. The bin histogram rides along with the degree histogram (same ei read).
__global__ __launch_bounds__(256) void k_prep(const float* __restrict__ W0, short* __restrict__ Wt0,
                                              const float* __restrict__ W1, short* __restrict__ Wt1,
                                              const float* __restrict__ W2, short* __restrict__ Wt2,
                                              const int* __restrict__ ei, int* __restrict__ deg,
                                              int* __restrict__ binCnt)
{
    int b = blockIdx.x;
    int tid = threadIdx.x;
    if (b < 256) {                         // Wt0[n][k] = bf16(W0[k][n]), 128x512
        int idx = b * 256 + tid;
        int n = idx >> 9, k = idx & 511;
        Wt0[idx] = f2b(W0[(size_t)k * HCH + n]);
        return;
    }
    b -= 256;
    if (b < 64) {                          // Wt1, 128x128
        int idx = b * 256 + tid;
        int n = idx >> 7, k = idx & 127;
        Wt1[idx] = f2b(W1[(size_t)k * HCH + n]);
        return;
    }
    b -= 64;
    if (b < 24) {                          // Wt2, 48(pad)x128, zero-fill cols >= 40
        int idx = b * 256 + tid;
        int n = idx >> 7, k = idx & 127;
        Wt2[idx] = f2b(n < NLBL ? W2[(size_t)k * NLBL + n] : 0.f);
        return;
    }
    b -= 24;
    {                                      // degree + bin histograms (uniform branch per block)
        __shared__ int bh[256];
        bh[tid] = 0;
        __syncthreads();
        int e = b * 256 + tid;
        if (e < ETOT) {
            int dst = (e < EE) ? ei[EE + e] : (e - EE);
            atomicAdd(&deg[dst], 1);
            atomicAdd(&bh[dst >> BSH], 1);
        }
        __syncthreads();
        if (tid < BINS && bh[tid]) atomicAdd(&binCnt[tid], bh[tid]);
    }
}

// ---------------- multi-block exclusive scan; block NCHK scans the bins -------------
__global__ __launch_bounds__(1024) void k_scan1(const int* __restrict__ deg,
                                                int* __restrict__ row_ptr,
                                                int* __restrict__ tot,
                                                const int* __restrict__ binCnt,
                                                int* __restrict__ binBase,
                                                int* __restrict__ binCur)
{
    __shared__ int sm[1024];
    int b = blockIdx.x, tid = threadIdx.x;
    if (b == NCHK) {                       // exclusive scan of 196 bin counts
        int v = (tid < BINS) ? binCnt[tid] : 0;
        sm[tid] = v;
        __syncthreads();
        for (int ofs = 1; ofs < 1024; ofs <<= 1) {
            int t = (tid >= ofs) ? sm[tid - ofs] : 0;
            __syncthreads();
            sm[tid] += t;
            __syncthreads();
        }
        if (tid < BINS) {
            int ex = sm[tid] - v;
            binBase[tid] = ex;
            binCur[tid]  = ex;
        }
        return;
    }
    int i0 = b * SCH + tid * 8;
    int v[8];
    int s = 0;
    #pragma unroll
    for (int j = 0; j < 8; ++j) {
        int i = i0 + j;
        v[j] = (i < NN) ? deg[i] : 0;
        s += v[j];
    }
    sm[tid] = s;
    __syncthreads();
    for (int ofs = 1; ofs < 1024; ofs <<= 1) {
        int t = (tid >= ofs) ? sm[tid - ofs] : 0;
        __syncthreads();
        sm[tid] += t;
        __syncthreads();
    }
    int excl = sm[tid] - s;
    #pragma unroll
    for (int j = 0; j < 8; ++j) {
        int i = i0 + j;
        if (i < NN) row_ptr[i] = excl;
        excl += v[j];
    }
    if (tid == 1023) tot[b] = sm[1023];
}

// fixup: each thread prefix-sums the 7 chunk totals in-register
__global__ __launch_bounds__(256) void k_scan3(int* __restrict__ row_ptr,
                                               const int* __restrict__ tot)
{
    int i = blockIdx.x * 256 + threadIdx.x;
    if (i >= NN) return;
    int chunk = i / SCH;
    int pre = 0, total = 0;
    #pragma unroll
    for (int c = 0; c < NCHK; ++c) {
        int t = tot[c];
        total += t;
        if (c < chunk) pre += t;
    }
    row_ptr[i] += pre;
    if (i == NN - 1) row_ptr[NN] = total;   // == ETOT
}

// ---------------- phase C: bin the edges (contiguous per-(block,bin) segments) ------------
__global__ __launch_bounds__(256) void k_bin(const int* __restrict__ ei,
                                             int* __restrict__ binCur,
                                             int2* __restrict__ binned)
{
    __shared__ int bh[256];
    __shared__ int bbase[256];
    int tid = threadIdx.x;
    int e0 = blockIdx.x * BCH;
    bh[tid] = 0;
    __syncthreads();
    int src[16], dst[16];
    #pragma unroll
    for (int q = 0; q < 16; ++q) {
        int e = e0 + q * 256 + tid;
        if (e < ETOT) {
            if (e < EE) { src[q] = ei[e]; dst[q] = ei[EE + e]; }
            else        { src[q] = dst[q] = e - EE; }
            atomicAdd(&bh[dst[q] >> BSH], 1);
        } else dst[q] = -1;
    }
    __syncthreads();
    if (bh[tid]) bbase[tid] = atomicAdd(&binCur[tid], bh[tid]);
    __syncthreads();
    bh[tid] = 0;
    __syncthreads();
    #pragma unroll
    for (int q = 0; q < 16; ++q) {
        if (dst[q] >= 0) {
            int bn = dst[q] >> BSH;
            int off = atomicAdd(&bh[bn], 1);
            binned[bbase[bn] + off] = make_int2(src[q], dst[q]);
        }
    }
}

// ---------------- phase D: per-bin scatter with LDS cursors (no global atomics) -----------
// Block b owns bin b (<=256 nodes): cursors in LDS; csr writes land in one ~17KB window
// -> L2 write-combining fills lines before eviction (kills the 16x write amplification).
__global__ __launch_bounds__(256) void k_scat2(const int2* __restrict__ binned,
                                               const int* __restrict__ binBase,
                                               const int* __restrict__ binCnt,
                                               const int* __restrict__ row_ptr,
                                               int* __restrict__ csr_src)
{
    __shared__ int curs[256];
    int b = blockIdx.x, tid = threadIdx.x;
    int nb0 = b << BSH;
    if (nb0 + tid < NN) curs[tid] = row_ptr[nb0 + tid];
    __syncthreads();
    int s = binBase[b];
    int t = s + binCnt[b];
    for (int j = s + tid; j < t; j += 256) {
        int2 ed = binned[j];
        int slot = atomicAdd(&curs[ed.y - nb0], 1);
        csr_src[slot] = ed.x;
    }
}

// ---------------- MFMA GEMM: both operands LDS-staged, KCH=128 (round-5 form) -------------
// (sched_barrier(0) pin reverted: round-9 showed it costs ~5-7us — m141 failure mode.)
// 512 threads = 8 waves (4 M x 2 N), block = 64 rows x 128 cols.
// Fused alpha epilogue: head hh = wn*4+t owns tile t's 16 cols -> 16-lane shfl reduce.
template<int KDIM, bool A_BF16>
__global__ __launch_bounds__(512, 4) void k_gemm2(const void* __restrict__ Ap,
                                                  const short* __restrict__ Wt,
                                                  short* __restrict__ C,
                                                  int M,
                                                  const float* __restrict__ a_s,
                                                  const float* __restrict__ a_d,
                                                  float* __restrict__ as_o,
                                                  float* __restrict__ ad_o)
{
    constexpr int KCH  = 128;              // k-chunk
    constexpr int NCH  = KDIM / KCH;       // chunks (layer0: 4, layer1: 1)
    constexpr int LROW = KCH + 8;          // shorts per LDS row (+pad: banks)
    __shared__ short As[64 * LROW];        // 17.4 KB
    __shared__ short Bs[128 * LROW];       // 34.8 KB  -> 52.2 KB total

    const int tid  = threadIdx.x;
    const int wv   = tid >> 6;
    const int lane = tid & 63;
    const int quad = lane >> 4;
    const int col  = lane & 15;
    const int wr   = wv >> 1;              // M-group 0..3  (16 rows each)
    const int wn   = wv & 1;               // N-group 0..1  (64 cols each)
    const int rowbase = blockIdx.x * 64;

    const float* Af = (const float*)Ap;
    const short* Ab = (const short*)Ap;

    float4 pa[4];                          // fp32 A staging regs (layer 0)
    bf16x8 pab[2];                         // bf16 A staging regs (layer 1)
    bf16x8 pb[4];                          // B staging regs

    auto loadA = [&](int c) {
        if constexpr (A_BF16) {
            #pragma unroll
            for (int r = 0; r < 2; ++r) {
                int gr = rowbase + r * 32 + (tid >> 4);
                gr = gr < M ? gr : M - 1;
                pab[r] = *(const bf16x8*)(Ab + (size_t)gr * KDIM + c * KCH + (tid & 15) * 8);
            }
        } else {
            #pragma unroll
            for (int r = 0; r < 4; ++r) {
                int gr = rowbase + r * 16 + (tid >> 5);
                gr = gr < M ? gr : M - 1;
                pa[r] = *(const float4*)(Af + (size_t)gr * KDIM + c * KCH + (tid & 31) * 4);
            }
        }
    };
    auto loadB = [&](int c) {
        #pragma unroll
        for (int r = 0; r < 4; ++r) {
            int n = r * 32 + (tid >> 4);
            pb[r] = *(const bf16x8*)(Wt + (size_t)n * KDIM + (size_t)c * KCH + (tid & 15) * 8);
        }
    };
    auto writeAB = [&]() {
        if constexpr (A_BF16) {
            #pragma unroll
            for (int r = 0; r < 2; ++r) {
                int row = r * 32 + (tid >> 4);
                *(bf16x8*)(As + row * LROW + (tid & 15) * 8) = pab[r];
            }
        } else {
            #pragma unroll
            for (int r = 0; r < 4; ++r) {
                int row = r * 16 + (tid >> 5);
                bf16x4 w;
                w[0] = f2b(pa[r].x); w[1] = f2b(pa[r].y);
                w[2] = f2b(pa[r].z); w[3] = f2b(pa[r].w);
                *(bf16x4*)(As + row * LROW + (tid & 31) * 4) = w;
            }
        }
        #pragma unroll
        for (int r = 0; r < 4; ++r) {
            int n = r * 32 + (tid >> 4);
            *(bf16x8*)(Bs + n * LROW + (tid & 15) * 8) = pb[r];
        }
    };

    f32x4 acc[4];
    #pragma unroll
    for (int t = 0; t < 4; ++t) acc[t] = (f32x4){0.f, 0.f, 0.f, 0.f};

    loadA(0); loadB(0);

    for (int c = 0; c < NCH; ++c) {
        writeAB();
        __syncthreads();
        if (c + 1 < NCH) { loadA(c + 1); loadB(c + 1); }   // fly under MFMA phase
        #pragma unroll
        for (int s = 0; s < KCH / 32; ++s) {
            bf16x8 af = *(const bf16x8*)(As + (wr * 16 + col) * LROW + s * 32 + quad * 8);
            #pragma unroll
            for (int t = 0; t < 4; ++t) {
                bf16x8 bf = *(const bf16x8*)(Bs + (wn * 64 + t * 16 + col) * LROW + s * 32 + quad * 8);
                acc[t] = __builtin_amdgcn_mfma_f32_16x16x32_bf16(af, bf, acc[t], 0, 0, 0);
            }
        }
        if (c + 1 < NCH) __syncthreads();
    }

    const int mb = rowbase + wr * 16 + quad * 4;

    // C write (bf16)
    #pragma unroll
    for (int t = 0; t < 4; ++t) {
        int cc = wn * 64 + t * 16 + col;
        #pragma unroll
        for (int r = 0; r < 4; ++r) {
            int m = mb + r;
            if (m < M) C[(size_t)m * HCH + cc] = f2b(acc[t][r]);
        }
    }

    // fused attention logits: head hh = wn*4+t; 16-lane reduce over col
    #pragma unroll
    for (int t = 0; t < 4; ++t) {
        int hh = wn * 4 + t;
        float ws = a_s[hh * HIDC + col];
        float wd = a_d[hh * HIDC + col];
        #pragma unroll
        for (int r = 0; r < 4; ++r) {
            float vs = acc[t][r] * ws;
            float vd = acc[t][r] * wd;
            vs += __shfl_xor(vs, 1);  vd += __shfl_xor(vd, 1);
            vs += __shfl_xor(vs, 2);  vd += __shfl_xor(vd, 2);
            vs += __shfl_xor(vs, 4);  vd += __shfl_xor(vd, 4);
            vs += __shfl_xor(vs, 8);  vd += __shfl_xor(vd, 8);
            int m = mb + r;
            if (col == 0 && m < M) {
                as_o[m * NH + hh] = vs;
                ad_o[m * NH + hh] = vd;
            }
        }
    }
}

// ---------------- layer-2 GEMM (N=48 padded tile) with fused alpha2 epilogue --------------
template<int KDIM, int NTILES>
__global__ __launch_bounds__(256) void k_gemm_lds(const short* __restrict__ Ab,
                                                  const short* __restrict__ Wt,
                                                  short* __restrict__ C,
                                                  int M, int N,
                                                  const float* __restrict__ a_s2,
                                                  const float* __restrict__ a_d2,
                                                  float* __restrict__ as_o,
                                                  float* __restrict__ ad_o)
{
    constexpr int NFULL = NTILES * 16;
    constexpr int KCH = 128;               // k-chunk
    constexpr int NK = KDIM / 32;          // total ksteps
    constexpr int NCH = KDIM / KCH;        // chunks
    constexpr int LROW = KCH + 8;          // shorts per LDS row
    __shared__ short Bs[NFULL * LROW];

    const int tid  = threadIdx.x;
    const int wave = tid >> 6;
    const int lane = tid & 63;
    const int quad = lane >> 4;
    const int col  = lane & 15;
    const int row  = blockIdx.x * 64 + wave * 16 + col;
    const int arow = row < M ? row : M - 1;

    f32x4 acc[NTILES];
    #pragma unroll
    for (int t = 0; t < NTILES; ++t) acc[t] = (f32x4){0.f, 0.f, 0.f, 0.f};

    bf16x8 arB[4];
    auto pf = [&](int ks) {
        if (ks >= NK) return;
        arB[ks & 3] = *(const bf16x8*)(Ab + (size_t)arow * KDIM + ks * 32 + quad * 8);
    };
    pf(0); pf(1); pf(2); pf(3);

    for (int c = 0; c < NCH; ++c) {
        const int k0 = c * KCH;
        constexpr int TOT8 = NFULL * (KCH / 8);
        #pragma unroll
        for (int i = tid; i < TOT8; i += 256) {
            int n  = i >> 4;
            int kk = i & 15;
            bf16x8 v = *(const bf16x8*)(Wt + (size_t)n * KDIM + k0 + kk * 8);
            *(bf16x8*)(Bs + n * LROW + kk * 8) = v;
        }
        __syncthreads();
        #pragma unroll
        for (int s = 0; s < KCH / 32; ++s) {
            const int ks = c * (KCH / 32) + s;
            bf16x8 afrag = arB[ks & 3];
            pf(ks + 4);
            #pragma unroll
            for (int t = 0; t < NTILES; ++t) {
                bf16x8 bfrag = *(const bf16x8*)(Bs + (t * 16 + col) * LROW + s * 32 + quad * 8);
                acc[t] = __builtin_amdgcn_mfma_f32_16x16x32_bf16(afrag, bfrag, acc[t], 0, 0, 0);
            }
        }
        if (c + 1 < NCH) __syncthreads();
    }

    const int mbase = blockIdx.x * 64 + wave * 16 + quad * 4;
    #pragma unroll
    for (int t = 0; t < NTILES; ++t) {
        int cc = t * 16 + col;
        if (cc < N) {
            #pragma unroll
            for (int r = 0; r < 4; ++r) {
                int m = mbase + r;
                if (m < M) C[(size_t)m * N + cc] = f2b(acc[t][r]);
            }
        }
    }

    // fused alpha2: single head spanning cols 0..39 (cols >= 40 have zero W -> acc==0)
    float vs[4] = {0.f, 0.f, 0.f, 0.f};
    float vd[4] = {0.f, 0.f, 0.f, 0.f};
    #pragma unroll
    for (int t = 0; t < NTILES; ++t) {
        int cc = t * 16 + col;
        float ws = cc < NLBL ? a_s2[cc] : 0.f;
        float wd = cc < NLBL ? a_d2[cc] : 0.f;
        #pragma unroll
        for (int r = 0; r < 4; ++r) {
            vs[r] += acc[t][r] * ws;
            vd[r] += acc[t][r] * wd;
        }
    }
    #pragma unroll
    for (int r = 0; r < 4; ++r) {
        float s = vs[r], d = vd[r];
        s += __shfl_xor(s, 1);  d += __shfl_xor(d, 1);
        s += __shfl_xor(s, 2);  d += __shfl_xor(d, 2);
        s += __shfl_xor(s, 4);  d += __shfl_xor(d, 4);
        s += __shfl_xor(s, 8);  d += __shfl_xor(d, 8);
        int m = mbase + r;
        if (col == 0 && m < M) {
            as_o[m] = s;
            ad_o[m] = d;
        }
    }
}

// ---------------- pull aggregation: half-wave per edge stream, 8-deep + 4-deep + singles ----
__global__ __launch_bounds__(256) void k_agg(const int* __restrict__ row_ptr,
                                             const int* __restrict__ csr_src,
                                             const unsigned short* __restrict__ h,
                                             const float* __restrict__ as,
                                             const float* __restrict__ ad,
                                             const float* __restrict__ b,
                                             const float* __restrict__ g,
                                             const float* __restrict__ be,
                                             const float* __restrict__ rm,
                                             const float* __restrict__ rv,
                                             short* __restrict__ out)
{
    int n = blockIdx.x * 4 + (threadIdx.x >> 6);
    if (n >= NN) return;
    int lane = threadIdx.x & 63;
    int half = lane >> 5;
    int c4 = lane & 31;                  // channel group: channels 4*c4 .. 4*c4+3
    int hh = c4 >> 2;                    // head
    float adv = ad[n * NH + hh];
    float a0 = 0.f, a1 = 0.f, a2 = 0.f, a3 = 0.f, sw = 0.f;
    int jb = row_ptr[n], je = row_ptr[n + 1];
    int j = jb + half;
    for (; j + 14 < je; j += 16) {       // 8 edges per stream
        int s[8];
        #pragma unroll
        for (int q = 0; q < 8; ++q) s[q] = csr_src[j + 2 * q];
        float l[8];
        uint2 u[8];
        #pragma unroll
        for (int q = 0; q < 8; ++q) {
            l[q] = as[s[q] * NH + hh] + adv;
            u[q] = *(const uint2*)(h + (size_t)s[q] * HCH + 4 * c4);
        }
        #pragma unroll
        for (int q = 0; q < 8; ++q) {
            float lq = l[q] > 0.f ? l[q] : NEG_SLOPE * l[q];
            float w = __expf(lq);
            sw += w;
            a0 += w * blo(u[q].x);
            a1 += w * bhi(u[q].x);
            a2 += w * blo(u[q].y);
            a3 += w * bhi(u[q].y);
        }
    }
    for (; j + 6 < je; j += 8) {         // 4 edges per stream
        int s0 = csr_src[j];
        int s1 = csr_src[j + 2];
        int s2 = csr_src[j + 4];
        int s3 = csr_src[j + 6];
        float l0 = as[s0 * NH + hh] + adv;
        float l1 = as[s1 * NH + hh] + adv;
        float l2 = as[s2 * NH + hh] + adv;
        float l3 = as[s3 * NH + hh] + adv;
        uint2 u0 = *(const uint2*)(h + (size_t)s0 * HCH + 4 * c4);
        uint2 u1 = *(const uint2*)(h + (size_t)s1 * HCH + 4 * c4);
        uint2 u2 = *(const uint2*)(h + (size_t)s2 * HCH + 4 * c4);
        uint2 u3 = *(const uint2*)(h + (size_t)s3 * HCH + 4 * c4);
        l0 = l0 > 0.f ? l0 : NEG_SLOPE * l0;
        l1 = l1 > 0.f ? l1 : NEG_SLOPE * l1;
        l2 = l2 > 0.f ? l2 : NEG_SLOPE * l2;
        l3 = l3 > 0.f ? l3 : NEG_SLOPE * l3;
        float w0 = __expf(l0), w1 = __expf(l1), w2 = __expf(l2), w3 = __expf(l3);
        sw += (w0 + w1) + (w2 + w3);
        a0 += w0 * blo(u0.x) + w1 * blo(u1.x) + w2 * blo(u2.x) + w3 * blo(u3.x);
        a1 += w0 * bhi(u0.x) + w1 * bhi(u1.x) + w2 * bhi(u2.x) + w3 * bhi(u3.x);
        a2 += w0 * blo(u0.y) + w1 * blo(u1.y) + w2 * blo(u2.y) + w3 * blo(u3.y);
        a3 += w0 * bhi(u0.y) + w1 * bhi(u1.y) + w2 * bhi(u2.y) + w3 * bhi(u3.y);
    }
    for (; j < je; j += 2) {
        int s0 = csr_src[j];
        float l0 = as[s0 * NH + hh] + adv;
        uint2 u0 = *(const uint2*)(h + (size_t)s0 * HCH + 4 * c4);
        l0 = l0 > 0.f ? l0 : NEG_SLOPE * l0;
        float w0 = __expf(l0);
        sw += w0;
        a0 += w0 * blo(u0.x);
        a1 += w0 * bhi(u0.x);
        a2 += w0 * blo(u0.y);
        a3 += w0 * bhi(u0.y);
    }
    // combine the two half-waves
    a0 += __shfl_down(a0, 32);
    a1 += __shfl_down(a1, 32);
    a2 += __shfl_down(a2, 32);
    a3 += __shfl_down(a3, 32);
    sw += __shfl_down(sw, 32);
    if (half == 0) {
        int c = 4 * c4;
        float inv = 1.f / (sw + 1e-16f);
        float4 bv  = *(const float4*)(b + c);
        float4 gv  = *(const float4*)(g + c);
        float4 bev = *(const float4*)(be + c);
        float4 rmv = *(const float4*)(rm + c);
        float4 rvv = *(const float4*)(rv + c);
        float r0 = a0 * inv + bv.x;
        float r1 = a1 * inv + bv.y;
        float r2 = a2 * inv + bv.z;
        float r3 = a3 * inv + bv.w;
        r0 = (r0 - rmv.x) * (gv.x * rsqrtf(rvv.x + BN_EPS)) + bev.x;
        r1 = (r1 - rmv.y) * (gv.y * rsqrtf(rvv.y + BN_EPS)) + bev.y;
        r2 = (r2 - rmv.z) * (gv.z * rsqrtf(rvv.z + BN_EPS)) + bev.z;
        r3 = (r3 - rmv.w) * (gv.w * rsqrtf(rvv.w + BN_EPS)) + bev.w;
        r0 = r0 > 0.f ? r0 : ELU_A * expm1f(r0);
        r1 = r1 > 0.f ? r1 : ELU_A * expm1f(r1);
        r2 = r2 > 0.f ? r2 : ELU_A * expm1f(r2);
        r3 = r3 > 0.f ? r3 : ELU_A * expm1f(r3);
        unsigned int lo = (unsigned int)(unsigned short)f2b(r0) |
                          ((unsigned int)(unsigned short)f2b(r1) << 16);
        unsigned int hi = (unsigned int)(unsigned short)f2b(r2) |
                          ((unsigned int)(unsigned short)f2b(r3) << 16);
        *(uint2*)(out + (size_t)n * HCH + c) = make_uint2(lo, hi);
    }
}

// layer-2: 1 head, 40 ch bf16 gather, 8-deep + 4-deep + singles, fp32 out
__global__ __launch_bounds__(256) void k_agg2(const int* __restrict__ row_ptr,
                                              const int* __restrict__ csr_src,
                                              const unsigned short* __restrict__ h2,
                                              const float* __restrict__ as,
                                              const float* __restrict__ ad,
                                              const float* __restrict__ b,
                                              float* __restrict__ out)
{
    int n = blockIdx.x * 4 + (threadIdx.x >> 6);
    if (n >= NN) return;
    int lane = threadIdx.x & 63;
    int half = lane >> 5;                // which edge stream
    int c2 = lane & 31;                  // channel-pair index; active if c2 < 20
    bool act = c2 < 20;
    int coff = act ? 2 * c2 : 0;
    float adv = ad[n];
    float acc0 = 0.f, acc1 = 0.f, sw = 0.f;
    int jb = row_ptr[n], je = row_ptr[n + 1];
    int j = jb + half;
    for (; j + 14 < je; j += 16) {       // 8 edges per stream
        int s[8];
        #pragma unroll
        for (int q = 0; q < 8; ++q) s[q] = csr_src[j + 2 * q];
        float l[8];
        unsigned int u[8];
        #pragma unroll
        for (int q = 0; q < 8; ++q) {
            l[q] = as[s[q]] + adv;
            u[q] = *(const unsigned int*)(h2 + (size_t)s[q] * NLBL + coff);
        }
        #pragma unroll
        for (int q = 0; q < 8; ++q) {
            float lq = l[q] > 0.f ? l[q] : NEG_SLOPE * l[q];
            float w = __expf(lq);
            sw += w;
            if (act) {
                acc0 += w * blo(u[q]);
                acc1 += w * bhi(u[q]);
            }
        }
    }
    for (; j + 6 < je; j += 8) {
        int s0 = csr_src[j];
        int s1 = csr_src[j + 2];
        int s2 = csr_src[j + 4];
        int s3 = csr_src[j + 6];
        float l0 = as[s0] + adv;
        float l1 = as[s1] + adv;
        float l2 = as[s2] + adv;
        float l3 = as[s3] + adv;
        unsigned int u0 = *(const unsigned int*)(h2 + (size_t)s0 * NLBL + coff);
        unsigned int u1 = *(const unsigned int*)(h2 + (size_t)s1 * NLBL + coff);
        unsigned int u2 = *(const unsigned int*)(h2 + (size_t)s2 * NLBL + coff);
        unsigned int u3 = *(const unsigned int*)(h2 + (size_t)s3 * NLBL + coff);
        l0 = l0 > 0.f ? l0 : NEG_SLOPE * l0;
        l1 = l1 > 0.f ? l1 : NEG_SLOPE * l1;
        l2 = l2 > 0.f ? l2 : NEG_SLOPE * l2;
        l3 = l3 > 0.f ? l3 : NEG_SLOPE * l3;
        float w0 = __expf(l0), w1 = __expf(l1), w2 = __expf(l2), w3 = __expf(l3);
        sw += (w0 + w1) + (w2 + w3);
        if (act) {
            acc0 += w0 * blo(u0) + w1 * blo(u1) + w2 * blo(u2) + w3 * blo(u3);
            acc1 += w0 * bhi(u0) + w1 * bhi(u1) + w2 * bhi(u2) + w3 * bhi(u3);
        }
    }
    for (; j < je; j += 2) {
        int s = csr_src[j];
        float l = as[s] + adv;
        unsigned int u = *(const unsigned int*)(h2 + (size_t)s * NLBL + coff);
        l = l > 0.f ? l : NEG_SLOPE * l;
        float w = __expf(l);
        sw += w;
        if (act) {
            acc0 += w * blo(u);
            acc1 += w * bhi(u);
        }
    }
    float acc0b = __shfl_down(acc0, 32);
    float acc1b = __shfl_down(acc1, 32);
    float swb   = __shfl_down(sw, 32);
    if (half == 0 && act) {
        acc0 += acc0b; acc1 += acc1b; sw += swb;
        float inv = 1.f / (sw + 1e-16f);
        out[(size_t)n * NLBL + 2 * c2]     = acc0 * inv + b[2 * c2];
        out[(size_t)n * NLBL + 2 * c2 + 1] = acc1 * inv + b[2 * c2 + 1];
    }
}

extern "C" void kernel_launch(void* const* d_in, const int* in_sizes, int n_in,
                              void* d_out, int out_size, void* d_ws, size_t ws_size,
                              hipStream_t stream)
{
    const float* x   = (const float*)d_in[0];
    const int*   ei  = (const int*)d_in[1];
    const float* W0  = (const float*)d_in[2];
    const float* as0 = (const float*)d_in[3];
    const float* ad0 = (const float*)d_in[4];
    const float* b0  = (const float*)d_in[5];
    const float* g0  = (const float*)d_in[6];
    const float* be0 = (const float*)d_in[7];
    const float* rm0 = (const float*)d_in[8];
    const float* rv0 = (const float*)d_in[9];
    const float* W1  = (const float*)d_in[10];
    const float* as1 = (const float*)d_in[11];
    const float* ad1 = (const float*)d_in[12];
    const float* b1  = (const float*)d_in[13];
    const float* g1  = (const float*)d_in[14];
    const float* be1 = (const float*)d_in[15];
    const float* rm1 = (const float*)d_in[16];
    const float* rv1 = (const float*)d_in[17];
    const float* W2  = (const float*)d_in[18];
    const float* a_s2 = (const float*)d_in[19];
    const float* a_d2 = (const float*)d_in[20];
    const float* b2  = (const float*)d_in[21];
    float* out = (float*)d_out;

    char* ws = (char*)d_ws;
    size_t off = 0;
    auto alloc = [&](size_t bytes) {
        void* p = (void*)(ws + off);
        off += (bytes + 255) & ~(size_t)255;
        return p;
    };
    short* hbuf   = (short*)alloc((size_t)NN * HCH * 2);   // bf16 GEMM out / gather source
    short* fbuf   = (short*)alloc((size_t)NN * HCH * 2);   // bf16 aggregated features (GEMM A input)
    float* asb    = (float*)alloc((size_t)NN * NH * 4);
    float* adb    = (float*)alloc((size_t)NN * NH * 4);
    int*   deg    = (int*)alloc((size_t)NN * 4);           // zeroed (with binCnt) below
    int*   binCnt = (int*)alloc(256 * 4);                  // contiguous with deg padding
    int*   rowp   = (int*)alloc((size_t)(NN + 1) * 4);
    int*   csrs   = (int*)alloc((size_t)ETOT * 4);
    int2*  binned = (int2*)alloc((size_t)ETOT * 8);
    int*   binBase = (int*)alloc(256 * 4);
    int*   binCur  = (int*)alloc(256 * 4);
    short* Wt0    = (short*)alloc((size_t)HCH * FIN * 2);
    short* Wt1    = (short*)alloc((size_t)HCH * HCH * 2);
    short* Wt2    = (short*)alloc((size_t)NLBLP * HCH * 2);
    int*   tot    = (int*)alloc(64 * 4);
    short* h2     = hbuf;   // reuse: hbuf dead by layer 2

    const int T = 256;
    const int gN4 = (NN + 3) / 4;
    const int gM  = (NN + 63) / 64;        // 782
    const int gE  = (ETOT + T - 1) / T;    // 3321
    const int gPrep = 256 + 64 + 24 + gE;  // 3665

    // ---------- prep: weight transpose/convert + degree/bin histograms (one launch) --------
    // deg and binCnt are adjacent allocations -> one memset covers both.
    hipMemsetAsync(deg, 0, (((size_t)NN * 4 + 255) & ~(size_t)255) + 256 * 4, stream);
    k_prep<<<gPrep, T, 0, stream>>>(W0, Wt0, W1, Wt1, W2, Wt2, ei, deg, binCnt);

    // ---------- scans + binned CSR build ----------
    k_scan1<<<NCHK + 1, 1024, 0, stream>>>(deg, rowp, tot, binCnt, binBase, binCur);
    k_scan3<<<(NN + T - 1) / T, T, 0, stream>>>(rowp, tot);
    k_bin<<<GBIN, T, 0, stream>>>(ei, binCur, binned);
    k_scat2<<<BINS, T, 0, stream>>>(binned, binBase, binCnt, rowp, csrs);

    // ---------- layer 0 (GEMM + fused alpha epilogue) ----------
    k_gemm2<FIN, false><<<gM, 512, 0, stream>>>(x, Wt0, hbuf, NN, as0, ad0, asb, adb);
    k_agg<<<gN4, T, 0, stream>>>(rowp, csrs, (const unsigned short*)hbuf, asb, adb,
                                 b0, g0, be0, rm0, rv0, fbuf);

    // ---------- layer 1 ----------
    k_gemm2<HCH, true><<<gM, 512, 0, stream>>>(fbuf, Wt1, hbuf, NN, as1, ad1, asb, adb);
    k_agg<<<gN4, T, 0, stream>>>(rowp, csrs, (const unsigned short*)hbuf, asb, adb,
                                 b1, g1, be1, rm1, rv1, fbuf);

    // ---------- layer 2 (GEMM + fused alpha2 epilogue) ----------
    k_gemm_lds<HCH, 3><<<gM, T, 0, stream>>>(fbuf, Wt2, h2, NN, NLBL,
                                             a_s2, a_d2, asb, adb);
    k_agg2<<<gN4, T, 0, stream>>>(rowp, csrs, (const unsigned short*)h2, asb, adb, b2, out);
}

// Round 11
// 437.291 us; speedup vs baseline: 1.1259x; 1.1259x over previous
//
#include <hip/hip_runtime.h>
#include <hip/hip_bf16.h>
#include <cstdint>
#include <cstddef>

#define NN 50000
#define EE 800000
#define FIN 512
#define HIDC 16
#define NH 8
#define HCH 128
#define NLBL 40
#define NLBLP 48
#define ETOT (EE + NN)
#define NEG_SLOPE 0.2f
#define ELU_A 0.2f
#define BN_EPS 1e-5f
#define SCH 8192
#define NCHK 7          // ceil(NN/SCH)
#define BSH 8           // bin = dst >> 8
#define BINS 196        // ceil(NN/256)
#define BCH 4096        // edges per k_bin block
#define GBIN ((ETOT + BCH - 1) / BCH)   // 208

typedef __attribute__((ext_vector_type(8))) short bf16x8;
typedef __attribute__((ext_vector_type(4))) short bf16x4;
typedef __attribute__((ext_vector_type(4))) float f32x4;

__device__ inline short f2b(float f) {
    __hip_bfloat16 h = __float2bfloat16(f);   // RNE
    return *reinterpret_cast<short*>(&h);
}
__device__ inline float blo(unsigned int u) {
    union { unsigned int u; float f; } v; v.u = u << 16; return v.f;
}
__device__ inline float bhi(unsigned int u) {
    union { unsigned int u; float f; } v; v.u = u & 0xffff0000u; return v.f;
}

// ---------------- fused prep: 3x weight transpose/convert + degree histogram ----------------
// (round-10 lesson: NO bin histogram here — 470K atomics on 196 addresses serialized
// cross-XCD, 92us. Bin bases fall out of the degree scan for free: bins are contiguous
// node ranges, so binBase[b] = row_ptr[b*256].)
__global__ __launch_bounds__(256) void k_prep(const float* __restrict__ W0, short* __restrict__ Wt0,
                                              const float* __restrict__ W1, short* __restrict__ Wt1,
                                              const float* __restrict__ W2, short* __restrict__ Wt2,
                                              const int* __restrict__ ei, int* __restrict__ deg)
{
    int b = blockIdx.x;
    int tid = threadIdx.x;
    if (b < 256) {                         // Wt0[n][k] = bf16(W0[k][n]), 128x512
        int idx = b * 256 + tid;
        int n = idx >> 9, k = idx & 511;
        Wt0[idx] = f2b(W0[(size_t)k * HCH + n]);
        return;
    }
    b -= 256;
    if (b < 64) {                          // Wt1, 128x128
        int idx = b * 256 + tid;
        int n = idx >> 7, k = idx & 127;
        Wt1[idx] = f2b(W1[(size_t)k * HCH + n]);
        return;
    }
    b -= 64;
    if (b < 24) {                          // Wt2, 48(pad)x128, zero-fill cols >= 40
        int idx = b * 256 + tid;
        int n = idx >> 7, k = idx & 127;
        Wt2[idx] = f2b(n < NLBL ? W2[(size_t)k * NLBL + n] : 0.f);
        return;
    }
    b -= 24;
    {                                      // degree histogram
        int e = b * 256 + tid;
        if (e < ETOT) {
            int dst = (e < EE) ? ei[EE + e] : (e - EE);
            atomicAdd(&deg[dst], 1);
        }
    }
}

// ---------------- multi-block exclusive scan ----------------
__global__ __launch_bounds__(1024) void k_scan1(const int* __restrict__ deg,
                                                int* __restrict__ row_ptr,
                                                int* __restrict__ tot)
{
    __shared__ int sm[1024];
    int b = blockIdx.x, tid = threadIdx.x;
    int i0 = b * SCH + tid * 8;
    int v[8];
    int s = 0;
    #pragma unroll
    for (int j = 0; j < 8; ++j) {
        int i = i0 + j;
        v[j] = (i < NN) ? deg[i] : 0;
        s += v[j];
    }
    sm[tid] = s;
    __syncthreads();
    for (int ofs = 1; ofs < 1024; ofs <<= 1) {
        int t = (tid >= ofs) ? sm[tid - ofs] : 0;
        __syncthreads();
        sm[tid] += t;
        __syncthreads();
    }
    int excl = sm[tid] - s;
    #pragma unroll
    for (int j = 0; j < 8; ++j) {
        int i = i0 + j;
        if (i < NN) row_ptr[i] = excl;
        excl += v[j];
    }
    if (tid == 1023) tot[b] = sm[1023];
}

// fixup: prefix-sum the 7 chunk totals in-register; also seed per-bin cursors
// (binCur[b] = final row_ptr[b*256] — bins are contiguous node ranges).
__global__ __launch_bounds__(256) void k_scan3(int* __restrict__ row_ptr,
                                               const int* __restrict__ tot,
                                               int* __restrict__ binCur)
{
    int i = blockIdx.x * 256 + threadIdx.x;
    if (i >= NN) return;
    int chunk = i / SCH;
    int pre = 0, total = 0;
    #pragma unroll
    for (int c = 0; c < NCHK; ++c) {
        int t = tot[c];
        total += t;
        if (c < chunk) pre += t;
    }
    int v = row_ptr[i] + pre;
    row_ptr[i] = v;
    if ((i & 255) == 0) binCur[i >> BSH] = v;
    if (i == NN - 1) row_ptr[NN] = total;   // == ETOT
}

// ---------------- phase C: bin the edges (contiguous per-(block,bin) segments) ------------
// binned[] shares the CSR index space: bin b's region is [row_ptr[b*256], row_ptr[(b+1)*256)).
__global__ __launch_bounds__(256) void k_bin(const int* __restrict__ ei,
                                             int* __restrict__ binCur,
                                             int2* __restrict__ binned)
{
    __shared__ int bh[256];
    __shared__ int bbase[256];
    int tid = threadIdx.x;
    int e0 = blockIdx.x * BCH;
    bh[tid] = 0;
    __syncthreads();
    int src[16], dst[16];
    #pragma unroll
    for (int q = 0; q < 16; ++q) {
        int e = e0 + q * 256 + tid;
        if (e < ETOT) {
            if (e < EE) { src[q] = ei[e]; dst[q] = ei[EE + e]; }
            else        { src[q] = dst[q] = e - EE; }
            atomicAdd(&bh[dst[q] >> BSH], 1);
        } else dst[q] = -1;
    }
    __syncthreads();
    if (bh[tid]) bbase[tid] = atomicAdd(&binCur[tid], bh[tid]);
    __syncthreads();
    bh[tid] = 0;
    __syncthreads();
    #pragma unroll
    for (int q = 0; q < 16; ++q) {
        if (dst[q] >= 0) {
            int bn = dst[q] >> BSH;
            int off = atomicAdd(&bh[bn], 1);
            binned[bbase[bn] + off] = make_int2(src[q], dst[q]);
        }
    }
}

// ---------------- phase D: per-bin scatter with LDS cursors (no global atomics) -----------
// Block b owns bin b (<=256 nodes): cursors in LDS; csr writes land in one ~17KB window
// -> L2 write-combining fills lines before eviction (kills the 16x write amplification).
__global__ __launch_bounds__(256) void k_scat2(const int2* __restrict__ binned,
                                               const int* __restrict__ row_ptr,
                                               int* __restrict__ csr_src)
{
    __shared__ int curs[256];
    int b = blockIdx.x, tid = threadIdx.x;
    int nb0 = b << BSH;
    if (nb0 + tid < NN) curs[tid] = row_ptr[nb0 + tid];
    __syncthreads();
    int s = row_ptr[nb0];
    int nend = nb0 + 256; if (nend > NN) nend = NN;
    int t = row_ptr[nend];
    for (int j = s + tid; j < t; j += 256) {
        int2 ed = binned[j];
        int slot = atomicAdd(&curs[ed.y - nb0], 1);
        csr_src[slot] = ed.x;
    }
}

// ---------------- MFMA GEMM: both operands LDS-staged, KCH=128 (round-5 form) -------------
// 512 threads = 8 waves (4 M x 2 N), block = 64 rows x 128 cols.
// Fused alpha epilogue: head hh = wn*4+t owns tile t's 16 cols -> 16-lane shfl reduce.
template<int KDIM, bool A_BF16>
__global__ __launch_bounds__(512, 4) void k_gemm2(const void* __restrict__ Ap,
                                                  const short* __restrict__ Wt,
                                                  short* __restrict__ C,
                                                  int M,
                                                  const float* __restrict__ a_s,
                                                  const float* __restrict__ a_d,
                                                  float* __restrict__ as_o,
                                                  float* __restrict__ ad_o)
{
    constexpr int KCH  = 128;              // k-chunk
    constexpr int NCH  = KDIM / KCH;       // chunks (layer0: 4, layer1: 1)
    constexpr int LROW = KCH + 8;          // shorts per LDS row (+pad: banks)
    __shared__ short As[64 * LROW];        // 17.4 KB
    __shared__ short Bs[128 * LROW];       // 34.8 KB  -> 52.2 KB total

    const int tid  = threadIdx.x;
    const int wv   = tid >> 6;
    const int lane = tid & 63;
    const int quad = lane >> 4;
    const int col  = lane & 15;
    const int wr   = wv >> 1;              // M-group 0..3  (16 rows each)
    const int wn   = wv & 1;               // N-group 0..1  (64 cols each)
    const int rowbase = blockIdx.x * 64;

    const float* Af = (const float*)Ap;
    const short* Ab = (const short*)Ap;

    float4 pa[4];                          // fp32 A staging regs (layer 0)
    bf16x8 pab[2];                         // bf16 A staging regs (layer 1)
    bf16x8 pb[4];                          // B staging regs

    auto loadA = [&](int c) {
        if constexpr (A_BF16) {
            #pragma unroll
            for (int r = 0; r < 2; ++r) {
                int gr = rowbase + r * 32 + (tid >> 4);
                gr = gr < M ? gr : M - 1;
                pab[r] = *(const bf16x8*)(Ab + (size_t)gr * KDIM + c * KCH + (tid & 15) * 8);
            }
        } else {
            #pragma unroll
            for (int r = 0; r < 4; ++r) {
                int gr = rowbase + r * 16 + (tid >> 5);
                gr = gr < M ? gr : M - 1;
                pa[r] = *(const float4*)(Af + (size_t)gr * KDIM + c * KCH + (tid & 31) * 4);
            }
        }
    };
    auto loadB = [&](int c) {
        #pragma unroll
        for (int r = 0; r < 4; ++r) {
            int n = r * 32 + (tid >> 4);
            pb[r] = *(const bf16x8*)(Wt + (size_t)n * KDIM + (size_t)c * KCH + (tid & 15) * 8);
        }
    };
    auto writeAB = [&]() {
        if constexpr (A_BF16) {
            #pragma unroll
            for (int r = 0; r < 2; ++r) {
                int row = r * 32 + (tid >> 4);
                *(bf16x8*)(As + row * LROW + (tid & 15) * 8) = pab[r];
            }
        } else {
            #pragma unroll
            for (int r = 0; r < 4; ++r) {
                int row = r * 16 + (tid >> 5);
                bf16x4 w;
                w[0] = f2b(pa[r].x); w[1] = f2b(pa[r].y);
                w[2] = f2b(pa[r].z); w[3] = f2b(pa[r].w);
                *(bf16x4*)(As + row * LROW + (tid & 31) * 4) = w;
            }
        }
        #pragma unroll
        for (int r = 0; r < 4; ++r) {
            int n = r * 32 + (tid >> 4);
            *(bf16x8*)(Bs + n * LROW + (tid & 15) * 8) = pb[r];
        }
    };

    f32x4 acc[4];
    #pragma unroll
    for (int t = 0; t < 4; ++t) acc[t] = (f32x4){0.f, 0.f, 0.f, 0.f};

    loadA(0); loadB(0);

    for (int c = 0; c < NCH; ++c) {
        writeAB();
        __syncthreads();
        if (c + 1 < NCH) { loadA(c + 1); loadB(c + 1); }   // fly under MFMA phase
        #pragma unroll
        for (int s = 0; s < KCH / 32; ++s) {
            bf16x8 af = *(const bf16x8*)(As + (wr * 16 + col) * LROW + s * 32 + quad * 8);
            #pragma unroll
            for (int t = 0; t < 4; ++t) {
                bf16x8 bf = *(const bf16x8*)(Bs + (wn * 64 + t * 16 + col) * LROW + s * 32 + quad * 8);
                acc[t] = __builtin_amdgcn_mfma_f32_16x16x32_bf16(af, bf, acc[t], 0, 0, 0);
            }
        }
        if (c + 1 < NCH) __syncthreads();
    }

    const int mb = rowbase + wr * 16 + quad * 4;

    // C write (bf16)
    #pragma unroll
    for (int t = 0; t < 4; ++t) {
        int cc = wn * 64 + t * 16 + col;
        #pragma unroll
        for (int r = 0; r < 4; ++r) {
            int m = mb + r;
            if (m < M) C[(size_t)m * HCH + cc] = f2b(acc[t][r]);
        }
    }

    // fused attention logits: head hh = wn*4+t; 16-lane reduce over col
    #pragma unroll
    for (int t = 0; t < 4; ++t) {
        int hh = wn * 4 + t;
        float ws = a_s[hh * HIDC + col];
        float wd = a_d[hh * HIDC + col];
        #pragma unroll
        for (int r = 0; r < 4; ++r) {
            float vs = acc[t][r] * ws;
            float vd = acc[t][r] * wd;
            vs += __shfl_xor(vs, 1);  vd += __shfl_xor(vd, 1);
            vs += __shfl_xor(vs, 2);  vd += __shfl_xor(vd, 2);
            vs += __shfl_xor(vs, 4);  vd += __shfl_xor(vd, 4);
            vs += __shfl_xor(vs, 8);  vd += __shfl_xor(vd, 8);
            int m = mb + r;
            if (col == 0 && m < M) {
                as_o[m * NH + hh] = vs;
                ad_o[m * NH + hh] = vd;
            }
        }
    }
}

// ---------------- layer-2 GEMM (N=48 padded tile) with fused alpha2 epilogue --------------
template<int KDIM, int NTILES>
__global__ __launch_bounds__(256) void k_gemm_lds(const short* __restrict__ Ab,
                                                  const short* __restrict__ Wt,
                                                  short* __restrict__ C,
                                                  int M, int N,
                                                  const float* __restrict__ a_s2,
                                                  const float* __restrict__ a_d2,
                                                  float* __restrict__ as_o,
                                                  float* __restrict__ ad_o)
{
    constexpr int NFULL = NTILES * 16;
    constexpr int KCH = 128;               // k-chunk
    constexpr int NK = KDIM / 32;          // total ksteps
    constexpr int NCH = KDIM / KCH;        // chunks
    constexpr int LROW = KCH + 8;          // shorts per LDS row
    __shared__ short Bs[NFULL * LROW];

    const int tid  = threadIdx.x;
    const int wave = tid >> 6;
    const int lane = tid & 63;
    const int quad = lane >> 4;
    const int col  = lane & 15;
    const int row  = blockIdx.x * 64 + wave * 16 + col;
    const int arow = row < M ? row : M - 1;

    f32x4 acc[NTILES];
    #pragma unroll
    for (int t = 0; t < NTILES; ++t) acc[t] = (f32x4){0.f, 0.f, 0.f, 0.f};

    bf16x8 arB[4];
    auto pf = [&](int ks) {
        if (ks >= NK) return;
        arB[ks & 3] = *(const bf16x8*)(Ab + (size_t)arow * KDIM + ks * 32 + quad * 8);
    };
    pf(0); pf(1); pf(2); pf(3);

    for (int c = 0; c < NCH; ++c) {
        const int k0 = c * KCH;
        constexpr int TOT8 = NFULL * (KCH / 8);
        #pragma unroll
        for (int i = tid; i < TOT8; i += 256) {
            int n  = i >> 4;
            int kk = i & 15;
            bf16x8 v = *(const bf16x8*)(Wt + (size_t)n * KDIM + k0 + kk * 8);
            *(bf16x8*)(Bs + n * LROW + kk * 8) = v;
        }
        __syncthreads();
        #pragma unroll
        for (int s = 0; s < KCH / 32; ++s) {
            const int ks = c * (KCH / 32) + s;
            bf16x8 afrag = arB[ks & 3];
            pf(ks + 4);
            #pragma unroll
            for (int t = 0; t < NTILES; ++t) {
                bf16x8 bfrag = *(const bf16x8*)(Bs + (t * 16 + col) * LROW + s * 32 + quad * 8);
                acc[t] = __builtin_amdgcn_mfma_f32_16x16x32_bf16(afrag, bfrag, acc[t], 0, 0, 0);
            }
        }
        if (c + 1 < NCH) __syncthreads();
    }

    const int mbase = blockIdx.x * 64 + wave * 16 + quad * 4;
    #pragma unroll
    for (int t = 0; t < NTILES; ++t) {
        int cc = t * 16 + col;
        if (cc < N) {
            #pragma unroll
            for (int r = 0; r < 4; ++r) {
                int m = mbase + r;
                if (m < M) C[(size_t)m * N + cc] = f2b(acc[t][r]);
            }
        }
    }

    // fused alpha2: single head spanning cols 0..39 (cols >= 40 have zero W -> acc==0)
    float vs[4] = {0.f, 0.f, 0.f, 0.f};
    float vd[4] = {0.f, 0.f, 0.f, 0.f};
    #pragma unroll
    for (int t = 0; t < NTILES; ++t) {
        int cc = t * 16 + col;
        float ws = cc < NLBL ? a_s2[cc] : 0.f;
        float wd = cc < NLBL ? a_d2[cc] : 0.f;
        #pragma unroll
        for (int r = 0; r < 4; ++r) {
            vs[r] += acc[t][r] * ws;
            vd[r] += acc[t][r] * wd;
        }
    }
    #pragma unroll
    for (int r = 0; r < 4; ++r) {
        float s = vs[r], d = vd[r];
        s += __shfl_xor(s, 1);  d += __shfl_xor(d, 1);
        s += __shfl_xor(s, 2);  d += __shfl_xor(d, 2);
        s += __shfl_xor(s, 4);  d += __shfl_xor(d, 4);
        s += __shfl_xor(s, 8);  d += __shfl_xor(d, 8);
        int m = mbase + r;
        if (col == 0 && m < M) {
            as_o[m] = s;
            ad_o[m] = d;
        }
    }
}

// ---------------- pull aggregation: half-wave per edge stream, 8-deep + 4-deep + singles ----
__global__ __launch_bounds__(256) void k_agg(const int* __restrict__ row_ptr,
                                             const int* __restrict__ csr_src,
                                             const unsigned short* __restrict__ h,
                                             const float* __restrict__ as,
                                             const float* __restrict__ ad,
                                             const float* __restrict__ b,
                                             const float* __restrict__ g,
                                             const float* __restrict__ be,
                                             const float* __restrict__ rm,
                                             const float* __restrict__ rv,
                                             short* __restrict__ out)
{
    int n = blockIdx.x * 4 + (threadIdx.x >> 6);
    if (n >= NN) return;
    int lane = threadIdx.x & 63;
    int half = lane >> 5;
    int c4 = lane & 31;                  // channel group: channels 4*c4 .. 4*c4+3
    int hh = c4 >> 2;                    // head
    float adv = ad[n * NH + hh];
    float a0 = 0.f, a1 = 0.f, a2 = 0.f, a3 = 0.f, sw = 0.f;
    int jb = row_ptr[n], je = row_ptr[n + 1];
    int j = jb + half;
    for (; j + 14 < je; j += 16) {       // 8 edges per stream
        int s[8];
        #pragma unroll
        for (int q = 0; q < 8; ++q) s[q] = csr_src[j + 2 * q];
        float l[8];
        uint2 u[8];
        #pragma unroll
        for (int q = 0; q < 8; ++q) {
            l[q] = as[s[q] * NH + hh] + adv;
            u[q] = *(const uint2*)(h + (size_t)s[q] * HCH + 4 * c4);
        }
        #pragma unroll
        for (int q = 0; q < 8; ++q) {
            float lq = l[q] > 0.f ? l[q] : NEG_SLOPE * l[q];
            float w = __expf(lq);
            sw += w;
            a0 += w * blo(u[q].x);
            a1 += w * bhi(u[q].x);
            a2 += w * blo(u[q].y);
            a3 += w * bhi(u[q].y);
        }
    }
    for (; j + 6 < je; j += 8) {         // 4 edges per stream
        int s0 = csr_src[j];
        int s1 = csr_src[j + 2];
        int s2 = csr_src[j + 4];
        int s3 = csr_src[j + 6];
        float l0 = as[s0 * NH + hh] + adv;
        float l1 = as[s1 * NH + hh] + adv;
        float l2 = as[s2 * NH + hh] + adv;
        float l3 = as[s3 * NH + hh] + adv;
        uint2 u0 = *(const uint2*)(h + (size_t)s0 * HCH + 4 * c4);
        uint2 u1 = *(const uint2*)(h + (size_t)s1 * HCH + 4 * c4);
        uint2 u2 = *(const uint2*)(h + (size_t)s2 * HCH + 4 * c4);
        uint2 u3 = *(const uint2*)(h + (size_t)s3 * HCH + 4 * c4);
        l0 = l0 > 0.f ? l0 : NEG_SLOPE * l0;
        l1 = l1 > 0.f ? l1 : NEG_SLOPE * l1;
        l2 = l2 > 0.f ? l2 : NEG_SLOPE * l2;
        l3 = l3 > 0.f ? l3 : NEG_SLOPE * l3;
        float w0 = __expf(l0), w1 = __expf(l1), w2 = __expf(l2), w3 = __expf(l3);
        sw += (w0 + w1) + (w2 + w3);
        a0 += w0 * blo(u0.x) + w1 * blo(u1.x) + w2 * blo(u2.x) + w3 * blo(u3.x);
        a1 += w0 * bhi(u0.x) + w1 * bhi(u1.x) + w2 * bhi(u2.x) + w3 * bhi(u3.x);
        a2 += w0 * blo(u0.y) + w1 * blo(u1.y) + w2 * blo(u2.y) + w3 * blo(u3.y);
        a3 += w0 * bhi(u0.y) + w1 * bhi(u1.y) + w2 * bhi(u2.y) + w3 * bhi(u3.y);
    }
    for (; j < je; j += 2) {
        int s0 = csr_src[j];
        float l0 = as[s0 * NH + hh] + adv;
        uint2 u0 = *(const uint2*)(h + (size_t)s0 * HCH + 4 * c4);
        l0 = l0 > 0.f ? l0 : NEG_SLOPE * l0;
        float w0 = __expf(l0);
        sw += w0;
        a0 += w0 * blo(u0.x);
        a1 += w0 * bhi(u0.x);
        a2 += w0 * blo(u0.y);
        a3 += w0 * bhi(u0.y);
    }
    // combine the two half-waves
    a0 += __shfl_down(a0, 32);
    a1 += __shfl_down(a1, 32);
    a2 += __shfl_down(a2, 32);
    a3 += __shfl_down(a3, 32);
    sw += __shfl_down(sw, 32);
    if (half == 0) {
        int c = 4 * c4;
        float inv = 1.f / (sw + 1e-16f);
        float4 bv  = *(const float4*)(b + c);
        float4 gv  = *(const float4*)(g + c);
        float4 bev = *(const float4*)(be + c);
        float4 rmv = *(const float4*)(rm + c);
        float4 rvv = *(const float4*)(rv + c);
        float r0 = a0 * inv + bv.x;
        float r1 = a1 * inv + bv.y;
        float r2 = a2 * inv + bv.z;
        float r3 = a3 * inv + bv.w;
        r0 = (r0 - rmv.x) * (gv.x * rsqrtf(rvv.x + BN_EPS)) + bev.x;
        r1 = (r1 - rmv.y) * (gv.y * rsqrtf(rvv.y + BN_EPS)) + bev.y;
        r2 = (r2 - rmv.z) * (gv.z * rsqrtf(rvv.z + BN_EPS)) + bev.z;
        r3 = (r3 - rmv.w) * (gv.w * rsqrtf(rvv.w + BN_EPS)) + bev.w;
        r0 = r0 > 0.f ? r0 : ELU_A * expm1f(r0);
        r1 = r1 > 0.f ? r1 : ELU_A * expm1f(r1);
        r2 = r2 > 0.f ? r2 : ELU_A * expm1f(r2);
        r3 = r3 > 0.f ? r3 : ELU_A * expm1f(r3);
        unsigned int lo = (unsigned int)(unsigned short)f2b(r0) |
                          ((unsigned int)(unsigned short)f2b(r1) << 16);
        unsigned int hi = (unsigned int)(unsigned short)f2b(r2) |
                          ((unsigned int)(unsigned short)f2b(r3) << 16);
        *(uint2*)(out + (size_t)n * HCH + c) = make_uint2(lo, hi);
    }
}

// layer-2: 1 head, 40 ch bf16 gather, 8-deep + 4-deep + singles, fp32 out
__global__ __launch_bounds__(256) void k_agg2(const int* __restrict__ row_ptr,
                                              const int* __restrict__ csr_src,
                                              const unsigned short* __restrict__ h2,
                                              const float* __restrict__ as,
                                              const float* __restrict__ ad,
                                              const float* __restrict__ b,
                                              float* __restrict__ out)
{
    int n = blockIdx.x * 4 + (threadIdx.x >> 6);
    if (n >= NN) return;
    int lane = threadIdx.x & 63;
    int half = lane >> 5;                // which edge stream
    int c2 = lane & 31;                  // channel-pair index; active if c2 < 20
    bool act = c2 < 20;
    int coff = act ? 2 * c2 : 0;
    float adv = ad[n];
    float acc0 = 0.f, acc1 = 0.f, sw = 0.f;
    int jb = row_ptr[n], je = row_ptr[n + 1];
    int j = jb + half;
    for (; j + 14 < je; j += 16) {       // 8 edges per stream
        int s[8];
        #pragma unroll
        for (int q = 0; q < 8; ++q) s[q] = csr_src[j + 2 * q];
        float l[8];
        unsigned int u[8];
        #pragma unroll
        for (int q = 0; q < 8; ++q) {
            l[q] = as[s[q]] + adv;
            u[q] = *(const unsigned int*)(h2 + (size_t)s[q] * NLBL + coff);
        }
        #pragma unroll
        for (int q = 0; q < 8; ++q) {
            float lq = l[q] > 0.f ? l[q] : NEG_SLOPE * l[q];
            float w = __expf(lq);
            sw += w;
            if (act) {
                acc0 += w * blo(u[q]);
                acc1 += w * bhi(u[q]);
            }
        }
    }
    for (; j + 6 < je; j += 8) {
        int s0 = csr_src[j];
        int s1 = csr_src[j + 2];
        int s2 = csr_src[j + 4];
        int s3 = csr_src[j + 6];
        float l0 = as[s0] + adv;
        float l1 = as[s1] + adv;
        float l2 = as[s2] + adv;
        float l3 = as[s3] + adv;
        unsigned int u0 = *(const unsigned int*)(h2 + (size_t)s0 * NLBL + coff);
        unsigned int u1 = *(const unsigned int*)(h2 + (size_t)s1 * NLBL + coff);
        unsigned int u2 = *(const unsigned int*)(h2 + (size_t)s2 * NLBL + coff);
        unsigned int u3 = *(const unsigned int*)(h2 + (size_t)s3 * NLBL + coff);
        l0 = l0 > 0.f ? l0 : NEG_SLOPE * l0;
        l1 = l1 > 0.f ? l1 : NEG_SLOPE * l1;
        l2 = l2 > 0.f ? l2 : NEG_SLOPE * l2;
        l3 = l3 > 0.f ? l3 : NEG_SLOPE * l3;
        float w0 = __expf(l0), w1 = __expf(l1), w2 = __expf(l2), w3 = __expf(l3);
        sw += (w0 + w1) + (w2 + w3);
        if (act) {
            acc0 += w0 * blo(u0) + w1 * blo(u1) + w2 * blo(u2) + w3 * blo(u3);
            acc1 += w0 * bhi(u0) + w1 * bhi(u1) + w2 * bhi(u2) + w3 * bhi(u3);
        }
    }
    for (; j < je; j += 2) {
        int s = csr_src[j];
        float l = as[s] + adv;
        unsigned int u = *(const unsigned int*)(h2 + (size_t)s * NLBL + coff);
        l = l > 0.f ? l : NEG_SLOPE * l;
        float w = __expf(l);
        sw += w;
        if (act) {
            acc0 += w * blo(u);
            acc1 += w * bhi(u);
        }
    }
    float acc0b = __shfl_down(acc0, 32);
    float acc1b = __shfl_down(acc1, 32);
    float swb   = __shfl_down(sw, 32);
    if (half == 0 && act) {
        acc0 += acc0b; acc1 += acc1b; sw += swb;
        float inv = 1.f / (sw + 1e-16f);
        out[(size_t)n * NLBL + 2 * c2]     = acc0 * inv + b[2 * c2];
        out[(size_t)n * NLBL + 2 * c2 + 1] = acc1 * inv + b[2 * c2 + 1];
    }
}

extern "C" void kernel_launch(void* const* d_in, const int* in_sizes, int n_in,
                              void* d_out, int out_size, void* d_ws, size_t ws_size,
                              hipStream_t stream)
{
    const float* x   = (const float*)d_in[0];
    const int*   ei  = (const int*)d_in[1];
    const float* W0  = (const float*)d_in[2];
    const float* as0 = (const float*)d_in[3];
    const float* ad0 = (const float*)d_in[4];
    const float* b0  = (const float*)d_in[5];
    const float* g0  = (const float*)d_in[6];
    const float* be0 = (const float*)d_in[7];
    const float* rm0 = (const float*)d_in[8];
    const float* rv0 = (const float*)d_in[9];
    const float* W1  = (const float*)d_in[10];
    const float* as1 = (const float*)d_in[11];
    const float* ad1 = (const float*)d_in[12];
    const float* b1  = (const float*)d_in[13];
    const float* g1  = (const float*)d_in[14];
    const float* be1 = (const float*)d_in[15];
    const float* rm1 = (const float*)d_in[16];
    const float* rv1 = (const float*)d_in[17];
    const float* W2  = (const float*)d_in[18];
    const float* a_s2 = (const float*)d_in[19];
    const float* a_d2 = (const float*)d_in[20];
    const float* b2  = (const float*)d_in[21];
    float* out = (float*)d_out;

    char* ws = (char*)d_ws;
    size_t off = 0;
    auto alloc = [&](size_t bytes) {
        void* p = (void*)(ws + off);
        off += (bytes + 255) & ~(size_t)255;
        return p;
    };
    short* hbuf   = (short*)alloc((size_t)NN * HCH * 2);   // bf16 GEMM out / gather source
    short* fbuf   = (short*)alloc((size_t)NN * HCH * 2);   // bf16 aggregated features (GEMM A input)
    float* asb    = (float*)alloc((size_t)NN * NH * 4);
    float* adb    = (float*)alloc((size_t)NN * NH * 4);
    int*   deg    = (int*)alloc((size_t)NN * 4);
    int*   rowp   = (int*)alloc((size_t)(NN + 1) * 4);
    int*   csrs   = (int*)alloc((size_t)ETOT * 4);
    int2*  binned = (int2*)alloc((size_t)ETOT * 8);
    int*   binCur = (int*)alloc(256 * 4);
    short* Wt0    = (short*)alloc((size_t)HCH * FIN * 2);
    short* Wt1    = (short*)alloc((size_t)HCH * HCH * 2);
    short* Wt2    = (short*)alloc((size_t)NLBLP * HCH * 2);
    int*   tot    = (int*)alloc(64 * 4);
    short* h2     = hbuf;   // reuse: hbuf dead by layer 2

    const int T = 256;
    const int gN4 = (NN + 3) / 4;
    const int gM  = (NN + 63) / 64;        // 782
    const int gE  = (ETOT + T - 1) / T;    // 3321
    const int gPrep = 256 + 64 + 24 + gE;  // 3665

    // ---------- prep: weight transpose/convert + degree histogram (one launch) ----------
    hipMemsetAsync(deg, 0, (size_t)NN * 4, stream);
    k_prep<<<gPrep, T, 0, stream>>>(W0, Wt0, W1, Wt1, W2, Wt2, ei, deg);

    // ---------- scans + binned CSR build ----------
    k_scan1<<<NCHK, 1024, 0, stream>>>(deg, rowp, tot);
    k_scan3<<<(NN + T - 1) / T, T, 0, stream>>>(rowp, tot, binCur);
    k_bin<<<GBIN, T, 0, stream>>>(ei, binCur, binned);
    k_scat2<<<BINS, T, 0, stream>>>(binned, rowp, csrs);

    // ---------- layer 0 (GEMM + fused alpha epilogue) ----------
    k_gemm2<FIN, false><<<gM, 512, 0, stream>>>(x, Wt0, hbuf, NN, as0, ad0, asb, adb);
    k_agg<<<gN4, T, 0, stream>>>(rowp, csrs, (const unsigned short*)hbuf, asb, adb,
                                 b0, g0, be0, rm0, rv0, fbuf);

    // ---------- layer 1 ----------
    k_gemm2<HCH, true><<<gM, 512, 0, stream>>>(fbuf, Wt1, hbuf, NN, as1, ad1, asb, adb);
    k_agg<<<gN4, T, 0, stream>>>(rowp, csrs, (const unsigned short*)hbuf, asb, adb,
                                 b1, g1, be1, rm1, rv1, fbuf);

    // ---------- layer 2 (GEMM + fused alpha2 epilogue) ----------
    k_gemm_lds<HCH, 3><<<gM, T, 0, stream>>>(fbuf, Wt2, h2, NN, NLBL,
                                             a_s2, a_d2, asb, adb);
    k_agg2<<<gN4, T, 0, stream>>>(rowp, csrs, (const unsigned short*)h2, asb, adb, b2, out);
}